// Round 8
// baseline (95.660 us; speedup 1.0000x reference)
//
#include <hip/hip_runtime.h>
#include <hip/hip_cooperative_groups.h>

namespace cg = cooperative_groups;

#define DIM 64
#define NPB 256           // nodes per bucket
#define NPB_SHIFT 8       // bin = dst >> 8
#define SEGCAP 4096       // pairs per bucket segment (mean ~3072, max ~3300)
#define SEG_SHIFT 12
#define THREADS 512
#define K2_U 8
#define K2_EPB (THREADS * K2_U)      // 4096 edges per bin chunk
#define SRC_BITS 17
#define SRC_MASK ((1u << SRC_BITS) - 1u)
#define NODE_ROWS 128     // rows per node chunk (4 rows/thread, 16 lanes/row)
#define OVF_CAP 8192

// One cooperative kernel:
//  P0: zero cursors (+ ovf counter), grid.sync
//  P1: blocks [0,SPLIT) grid-stride edge-binning chunks;
//      blocks [SPLIT,G) grid-stride node-score chunks.   grid.sync
//  P2: grid-stride buckets: dense strip read, L2 gather s[src],
//      LDS accumulate, plain RMW of disjoint out slice.
__global__ __launch_bounds__(THREADS)
void mega_kernel(const float4* __restrict__ x4,
                 const float4* __restrict__ Wrel4,
                 const float* __restrict__ b_rel,
                 const float4* __restrict__ Wroot4,
                 const int* __restrict__ ei,
                 float* __restrict__ s,
                 float* __restrict__ out,
                 int* __restrict__ cursor,      // NB+1 ints (last = ovf_cnt)
                 unsigned* __restrict__ bucket,
                 uint2* __restrict__ ovf,
                 int E, int NB, int NBINCH, int NODECH, int SPLIT, int n) {
    __shared__ unsigned lpair[K2_EPB];  // 16 KB
    __shared__ int  lga[K2_EPB];        // 16 KB
    __shared__ int  hist[THREADS];      // 2 KB
    __shared__ int  start[THREADS];     // 2 KB
    __shared__ int  wsum[8];
    __shared__ float acc[NPB];          // 1 KB (gather phase)

    cg::grid_group grid = cg::this_grid();
    int tid = threadIdx.x;
    int G = gridDim.x;
    int* ovf_cnt = cursor + NB;

    // ---------------- P0: zero cursors ----------------
    for (int i = blockIdx.x * THREADS + tid; i < NB + 1; i += G * THREADS)
        cursor[i] = 0;
    grid.sync();

    // ---------------- P1: fused binning + node scores ----------------
    if (blockIdx.x < SPLIT) {
        for (int blk = blockIdx.x; blk < NBINCH; blk += SPLIT) {
            hist[tid] = 0;
            __syncthreads();                               // barrier 1

            int base = blk * K2_EPB + tid * K2_U;
            int dst[K2_U], src[K2_U], rnk[K2_U], bin[K2_U];
            int have = 0;

            if (base + K2_U <= E) {
                const int4* sv = (const int4*)ei;          // src row
                const int4* dv = (const int4*)(ei + E);    // dst row
                int g = base >> 2;
                int4 s0 = sv[g], s1 = sv[g + 1];
                int4 d0 = dv[g], d1 = dv[g + 1];
                src[0] = s0.x; src[1] = s0.y; src[2] = s0.z; src[3] = s0.w;
                src[4] = s1.x; src[5] = s1.y; src[6] = s1.z; src[7] = s1.w;
                dst[0] = d0.x; dst[1] = d0.y; dst[2] = d0.z; dst[3] = d0.w;
                dst[4] = d1.x; dst[5] = d1.y; dst[6] = d1.z; dst[7] = d1.w;
                have = K2_U;
            } else {
                #pragma unroll
                for (int k = 0; k < K2_U; ++k) {
                    int e = base + k;
                    if (e < E) {
                        src[k] = ei[e];
                        dst[k] = ei[E + e];
                        have = k + 1;
                    }
                }
            }

            #pragma unroll
            for (int k = 0; k < K2_U; ++k) {
                if (k < have) {
                    bin[k] = dst[k] >> NPB_SHIFT;
                    rnk[k] = atomicAdd(&hist[bin[k]], 1);
                }
            }
            __syncthreads();                               // barrier 2

            int h = hist[tid];
            if (tid < NB && h > 0) start[tid] = atomicAdd(&cursor[tid], h);

            // per-wave inclusive scan (no barriers)
            int lane = tid & 63;
            int w = tid >> 6;
            int incl = h;
            #pragma unroll
            for (int off = 1; off < 64; off <<= 1) {
                int v = __shfl_up(incl, off);
                if (lane >= off) incl += v;
            }
            if (lane == 63) wsum[w] = incl;
            __syncthreads();                               // barrier 3

            int wb = 0;
            #pragma unroll
            for (int i = 0; i < 8; ++i) wb += (i < w) ? wsum[i] : 0;
            hist[tid] = wb + incl - h;                     // exclusive LDS base
            __syncthreads();                               // barrier 4

            #pragma unroll
            for (int k = 0; k < K2_U; ++k) {
                if (k < have) {
                    int b = bin[k];
                    int slot = hist[b] + rnk[k];
                    int gofs = start[b] + rnk[k];
                    if (gofs < SEGCAP) {
                        lpair[slot] = ((unsigned)(dst[k] & (NPB - 1)) << SRC_BITS)
                                      | (unsigned)src[k];
                        lga[slot] = (b << SEG_SHIFT) + gofs;
                    } else {   // statistically never; s-free correctness net
                        lga[slot] = -1;
                        int o = atomicAdd(ovf_cnt, 1);
                        if (o < OVF_CAP) ovf[o] = make_uint2((unsigned)dst[k],
                                                             (unsigned)src[k]);
                    }
                }
            }
            __syncthreads();                               // barrier 5

            int nE = min(K2_EPB, E - blk * K2_EPB);
            for (int i = tid; i < nE; i += THREADS) {
                int ga = lga[i];
                if (ga >= 0) bucket[ga] = lpair[i];
            }
            // next iter's barrier 1 protects lpair/lga reuse
        }
    } else {
        int nodeBlocks = G - SPLIT;
        int lane16 = tid & 15;
        int rg = tid >> 4;                  // 0..31
        float4 wr = Wrel4[lane16];
        float4 wt = Wroot4[lane16];
        float b0 = b_rel[0];

        for (int nc = blockIdx.x - SPLIT; nc < NODECH; nc += nodeBlocks) {
            int rowbase = nc * NODE_ROWS + rg;
            float4 xv[4];
            int row[4];
            #pragma unroll
            for (int k = 0; k < 4; ++k) {
                row[k] = rowbase + k * 32;
                xv[k] = (row[k] < n) ? x4[(size_t)row[k] * (DIM / 4) + lane16]
                                     : make_float4(0.f, 0.f, 0.f, 0.f);
            }
            #pragma unroll
            for (int k = 0; k < 4; ++k) {
                float sr = xv[k].x * wr.x + xv[k].y * wr.y
                         + xv[k].z * wr.z + xv[k].w * wr.w;
                float st = xv[k].x * wt.x + xv[k].y * wt.y
                         + xv[k].z * wt.z + xv[k].w * wt.w;
                #pragma unroll
                for (int off = 1; off < 16; off <<= 1) {
                    sr += __shfl_xor(sr, off);
                    st += __shfl_xor(st, off);
                }
                if (lane16 == 0 && row[k] < n) {
                    s[row[k]]   = sr;
                    out[row[k]] = st + b0;
                }
            }
        }
    }
    grid.sync();

    // ---------------- P2: per-bucket gather ----------------
    int oc = min(*ovf_cnt, OVF_CAP);   // usually 0
    for (int b = blockIdx.x; b < NB; b += G) {
        if (tid < NPB) acc[tid] = 0.f;
        __syncthreads();

        int total = min(cursor[b], SEGCAP);
        const unsigned* seg = bucket + ((size_t)b << SEG_SHIFT);

        int i = tid;
        for (; i + 3 * THREADS < total; i += 4 * THREADS) {
            unsigned p0 = seg[i];
            unsigned p1 = seg[i + THREADS];
            unsigned p2 = seg[i + 2 * THREADS];
            unsigned p3 = seg[i + 3 * THREADS];
            float v0 = s[p0 & SRC_MASK];
            float v1 = s[p1 & SRC_MASK];
            float v2 = s[p2 & SRC_MASK];
            float v3 = s[p3 & SRC_MASK];
            atomicAdd(&acc[p0 >> SRC_BITS], v0);
            atomicAdd(&acc[p1 >> SRC_BITS], v1);
            atomicAdd(&acc[p2 >> SRC_BITS], v2);
            atomicAdd(&acc[p3 >> SRC_BITS], v3);
        }
        for (; i < total; i += THREADS) {
            unsigned p = seg[i];
            atomicAdd(&acc[p >> SRC_BITS], s[p & SRC_MASK]);
        }

        for (int j = tid; j < oc; j += THREADS) {
            uint2 p = ovf[j];
            if ((int)(p.x >> NPB_SHIFT) == b)
                atomicAdd(&acc[p.x & (NPB - 1)], s[p.y]);
        }
        __syncthreads();

        if (tid < NPB) {
            int g = b * NPB + tid;
            if (g < n) out[g] += acc[tid];
        }
        __syncthreads();   // protect acc reuse on next grid-stride iter
    }
}

extern "C" void kernel_launch(void* const* d_in, const int* in_sizes, int n_in,
                              void* d_out, int out_size, void* d_ws, size_t ws_size,
                              hipStream_t stream) {
    const float* x      = (const float*)d_in[0];
    const int*   ei     = (const int*)d_in[1];
    const float* W_rel  = (const float*)d_in[2];
    const float* b_rel  = (const float*)d_in[3];
    const float* W_root = (const float*)d_in[4];
    float* out = (float*)d_out;

    int n = out_size;                 // N_NODES = 100000
    int E = in_sizes[1] / 2;          // 1200000

    int NB = (n + NPB - 1) / NPB;     // 391 buckets (<= THREADS required)

    // ws layout: s [n f32] | cursor [NB+1 int] | ovf [OVF_CAP uint2] | bucket
    float* s = (float*)d_ws;
    size_t off = ((size_t)n * 4 + 255) & ~(size_t)255;
    int* cursor = (int*)((char*)d_ws + off);
    off += ((size_t)(NB + 1) * 4 + 255) & ~(size_t)255;
    uint2* ovf = (uint2*)((char*)d_ws + off);
    off += ((size_t)OVF_CAP * sizeof(uint2) + 255) & ~(size_t)255;
    unsigned* bucket = (unsigned*)((char*)d_ws + off);

    int NBINCH = (E + K2_EPB - 1) / K2_EPB;           // 293
    int NODECH = (n + NODE_ROWS - 1) / NODE_ROWS;     // 782

    // Occupancy-derived cooperative grid (residency guaranteed).
    int dev = 0;
    hipGetDevice(&dev);
    int numCU = 0;
    hipDeviceGetAttribute(&numCU, hipDeviceAttributeMultiprocessorCount, dev);
    if (numCU <= 0) numCU = 256;
    int perCU = 0;
    hipOccupancyMaxActiveBlocksPerMultiprocessor(&perCU, mega_kernel, THREADS, 0);
    if (perCU < 1) perCU = 1;
    int G = numCU * perCU;

    // Work-balanced role split: binning chunks vs node chunks.
    int SPLIT = (int)((long long)G * NBINCH / (NBINCH + NODECH));
    if (SPLIT < 1) SPLIT = 1;
    if (SPLIT > G - 1) SPLIT = G - 1;

    void* args[] = {
        (void*)&x, (void*)&W_rel, (void*)&b_rel, (void*)&W_root,
        (void*)&ei, (void*)&s, (void*)&out, (void*)&cursor, (void*)&bucket,
        (void*)&ovf, (void*)&E, (void*)&NB, (void*)&NBINCH, (void*)&NODECH,
        (void*)&SPLIT, (void*)&n
    };
    hipLaunchCooperativeKernel((void*)mega_kernel, dim3(G), dim3(THREADS),
                               args, 0, stream);
}

// Round 9
// 35.229 us; speedup vs baseline: 2.7154x; 2.7154x over previous
//
#include <hip/hip_runtime.h>

#define DIM 64
#define NPB 256           // nodes per bucket
#define NPB_SHIFT 8       // bin = dst >> 8
#define SEGCAP 4096       // pairs per bucket segment (mean ~3072, max ~3300)
#define SEG_SHIFT 12
#define THREADS 512
#define K2_U 8
#define K2_EPB (THREADS * K2_U)      // 4096 edges per bin-block
#define SRC_BITS 17
#define SRC_MASK ((1u << SRC_BITS) - 1u)
#define NODE_ROWS 128     // rows per node-score block (4 rows/thread)
#define OVF_CAP 8192

// Fused kernel: blocks [0,NBLK) bin edges into dense bucket segments;
// blocks [NBLK, NBLK+NODEBLKS) compute per-node scores + out init.
// The two phases are data-independent (binning does not read s).
__global__ __launch_bounds__(THREADS)
void fused_kernel(const float4* __restrict__ x4,
                  const float4* __restrict__ Wrel4,
                  const float* __restrict__ b_rel,
                  const float4* __restrict__ Wroot4,
                  const int* __restrict__ ei,
                  float* __restrict__ s,
                  float* __restrict__ out,
                  int* __restrict__ cursor,      // NB ints, pre-zeroed
                  unsigned* __restrict__ bucket,
                  uint2* __restrict__ ovf,       // overflow list
                  int* __restrict__ ovf_cnt,     // pre-zeroed
                  int E, int NB, int NBLK, int n) {
    __shared__ unsigned lpair[K2_EPB];  // 16 KB
    __shared__ int  lga[K2_EPB];        // 16 KB
    __shared__ int  hist[THREADS];      // 2 KB (reused as exclusive base)
    __shared__ int  start[THREADS];     // 2 KB
    __shared__ int  wsum[8];

    int tid = threadIdx.x;

    if (blockIdx.x < NBLK) {
        // ---------------- binning phase ----------------
        int blk = blockIdx.x;
        hist[tid] = 0;
        __syncthreads();                               // barrier 1

        int base = blk * K2_EPB + tid * K2_U;
        int dst[K2_U], src[K2_U], rnk[K2_U], bin[K2_U];
        int have = 0;

        if (base + K2_U <= E) {
            const int4* sv = (const int4*)ei;          // src row
            const int4* dv = (const int4*)(ei + E);    // dst row
            int g = base >> 2;
            int4 s0 = sv[g], s1 = sv[g + 1];
            int4 d0 = dv[g], d1 = dv[g + 1];
            src[0] = s0.x; src[1] = s0.y; src[2] = s0.z; src[3] = s0.w;
            src[4] = s1.x; src[5] = s1.y; src[6] = s1.z; src[7] = s1.w;
            dst[0] = d0.x; dst[1] = d0.y; dst[2] = d0.z; dst[3] = d0.w;
            dst[4] = d1.x; dst[5] = d1.y; dst[6] = d1.z; dst[7] = d1.w;
            have = K2_U;
        } else {
            #pragma unroll
            for (int k = 0; k < K2_U; ++k) {
                int e = base + k;
                if (e < E) {
                    src[k] = ei[e];
                    dst[k] = ei[E + e];
                    have = k + 1;
                }
            }
        }

        #pragma unroll
        for (int k = 0; k < K2_U; ++k) {
            if (k < have) {
                bin[k] = dst[k] >> NPB_SHIFT;
                rnk[k] = atomicAdd(&hist[bin[k]], 1);
            }
        }
        __syncthreads();                               // barrier 2

        int h = hist[tid];
        if (tid < NB && h > 0) start[tid] = atomicAdd(&cursor[tid], h);

        // per-wave inclusive scan (no barriers)
        int lane = tid & 63;
        int w = tid >> 6;
        int incl = h;
        #pragma unroll
        for (int off = 1; off < 64; off <<= 1) {
            int v = __shfl_up(incl, off);
            if (lane >= off) incl += v;
        }
        if (lane == 63) wsum[w] = incl;
        __syncthreads();                               // barrier 3

        int wb = 0;
        #pragma unroll
        for (int i = 0; i < 8; ++i) wb += (i < w) ? wsum[i] : 0;
        hist[tid] = wb + incl - h;                     // exclusive LDS base
        __syncthreads();                               // barrier 4

        #pragma unroll
        for (int k = 0; k < K2_U; ++k) {
            if (k < have) {
                int b = bin[k];
                int slot = hist[b] + rnk[k];
                int gofs = start[b] + rnk[k];
                if (gofs < SEGCAP) {
                    lpair[slot] = ((unsigned)(dst[k] & (NPB - 1)) << SRC_BITS)
                                  | (unsigned)src[k];
                    lga[slot] = (b << SEG_SHIFT) + gofs;
                } else {   // statistically never; s-free correctness net
                    lga[slot] = -1;
                    int o = atomicAdd(ovf_cnt, 1);
                    if (o < OVF_CAP) ovf[o] = make_uint2((unsigned)dst[k],
                                                         (unsigned)src[k]);
                }
            }
        }
        __syncthreads();                               // barrier 5

        int nE = min(K2_EPB, E - blk * K2_EPB);
        for (int i = tid; i < nE; i += THREADS) {
            int ga = lga[i];
            if (ga >= 0) bucket[ga] = lpair[i];
        }
    } else {
        // ---------------- node-score phase ----------------
        // 16 lanes per row, 4 rows per thread (independent loads in flight).
        int nb = blockIdx.x - NBLK;
        int lane16 = tid & 15;
        int rg = tid >> 4;                  // 0..31
        int rowbase = nb * NODE_ROWS + rg;
        float4 wr = Wrel4[lane16];
        float4 wt = Wroot4[lane16];
        float b0 = b_rel[0];

        float4 xv[4];
        int row[4];
        #pragma unroll
        for (int k = 0; k < 4; ++k) {
            row[k] = rowbase + k * 32;
            xv[k] = (row[k] < n) ? x4[(size_t)row[k] * (DIM / 4) + lane16]
                                 : make_float4(0.f, 0.f, 0.f, 0.f);
        }
        #pragma unroll
        for (int k = 0; k < 4; ++k) {
            float sr = xv[k].x * wr.x + xv[k].y * wr.y
                     + xv[k].z * wr.z + xv[k].w * wr.w;
            float st = xv[k].x * wt.x + xv[k].y * wt.y
                     + xv[k].z * wt.z + xv[k].w * wt.w;
            #pragma unroll
            for (int off = 1; off < 16; off <<= 1) {
                sr += __shfl_xor(sr, off);
                st += __shfl_xor(st, off);
            }
            if (lane16 == 0 && row[k] < n) {
                s[row[k]]   = sr;
                out[row[k]] = st + b0;
            }
        }
    }
}

// Gather: one 512-thread block per bucket. uint4 strip loads (4 pairs per
// 16B load -> 4 independent L2 s-gathers + 4 LDS atomics in flight), LDS
// accumulate, plain RMW of disjoint out slice. Overflow list (usually empty)
// filtered per-bucket to stay race-free.
__global__ __launch_bounds__(THREADS)
void gather_kernel(const int* __restrict__ cursor,
                   const unsigned* __restrict__ bucket,
                   const float* __restrict__ s,
                   float* __restrict__ out,
                   const uint2* __restrict__ ovf,
                   const int* __restrict__ ovf_cnt,
                   int n) {
    __shared__ float acc[NPB];
    int b = blockIdx.x;
    int tid = threadIdx.x;

    if (tid < NPB) acc[tid] = 0.f;
    __syncthreads();

    int total = min(cursor[b], SEGCAP);
    const unsigned* seg = bucket + ((size_t)b << SEG_SHIFT);
    const uint4* seg4 = (const uint4*)seg;

    int nvec = total >> 2;
    for (int i = tid; i < nvec; i += THREADS) {
        uint4 q = seg4[i];
        float v0 = s[q.x & SRC_MASK];
        float v1 = s[q.y & SRC_MASK];
        float v2 = s[q.z & SRC_MASK];
        float v3 = s[q.w & SRC_MASK];
        atomicAdd(&acc[q.x >> SRC_BITS], v0);
        atomicAdd(&acc[q.y >> SRC_BITS], v1);
        atomicAdd(&acc[q.z >> SRC_BITS], v2);
        atomicAdd(&acc[q.w >> SRC_BITS], v3);
    }
    for (int i = (nvec << 2) + tid; i < total; i += THREADS) {
        unsigned p = seg[i];
        atomicAdd(&acc[p >> SRC_BITS], s[p & SRC_MASK]);
    }

    int oc = min(*ovf_cnt, OVF_CAP);   // usually 0
    for (int j = tid; j < oc; j += THREADS) {
        uint2 p = ovf[j];
        if ((int)(p.x >> NPB_SHIFT) == b)
            atomicAdd(&acc[p.x & (NPB - 1)], s[p.y]);
    }
    __syncthreads();

    if (tid < NPB) {
        int g = b * NPB + tid;
        if (g < n) out[g] += acc[tid];
    }
}

extern "C" void kernel_launch(void* const* d_in, const int* in_sizes, int n_in,
                              void* d_out, int out_size, void* d_ws, size_t ws_size,
                              hipStream_t stream) {
    const float* x      = (const float*)d_in[0];
    const int*   ei     = (const int*)d_in[1];
    const float* W_rel  = (const float*)d_in[2];
    const float* b_rel  = (const float*)d_in[3];
    const float* W_root = (const float*)d_in[4];
    float* out = (float*)d_out;

    int n = out_size;                 // N_NODES = 100000
    int E = in_sizes[1] / 2;          // 1200000

    int NB = (n + NPB - 1) / NPB;     // 391 buckets (<= THREADS required)

    // ws layout: s [n f32] | cursor [NB int] + ovf_cnt [1 int] | ovf | bucket
    float* s = (float*)d_ws;
    size_t off = ((size_t)n * 4 + 255) & ~(size_t)255;
    int* cursor = (int*)((char*)d_ws + off);
    int* ovf_cnt = cursor + NB;
    size_t zero_bytes = (size_t)(NB + 1) * sizeof(int);
    off += (zero_bytes + 255) & ~(size_t)255;
    uint2* ovf = (uint2*)((char*)d_ws + off);
    off += ((size_t)OVF_CAP * sizeof(uint2) + 255) & ~(size_t)255;
    unsigned* bucket = (unsigned*)((char*)d_ws + off);

    // 0) zero cursors + overflow counter (tiny, graph-capture-safe)
    hipMemsetAsync(cursor, 0, zero_bytes, stream);

    // 1) fused: binning blocks first, node-score blocks behind them
    int NBLK = (E + K2_EPB - 1) / K2_EPB;            // 293
    int NODEBLKS = (n + NODE_ROWS - 1) / NODE_ROWS;  // 782
    fused_kernel<<<NBLK + NODEBLKS, THREADS, 0, stream>>>(
        (const float4*)x, (const float4*)W_rel, b_rel, (const float4*)W_root,
        ei, s, out, cursor, bucket, ovf, ovf_cnt, E, NB, NBLK, n);

    // 2) per-bucket accumulate + disjoint out RMW (512 threads/bucket)
    gather_kernel<<<NB, THREADS, 0, stream>>>(cursor, bucket, s, out, ovf, ovf_cnt, n);
}

// Round 10
// 31.967 us; speedup vs baseline: 2.9924x; 1.1020x over previous
//
#include <hip/hip_runtime.h>

#define DIM 64
#define NPB 256           // nodes per bucket
#define NPB_SHIFT 8       // bin = dst >> 8
#define THREADS 512
#define K2_U 8
#define K2_EPB (THREADS * K2_U)   // 4096 edges per bin-block = strip size
#define STRIP K2_EPB
#define SRC_BITS 17
#define SRC_MASK ((1u << SRC_BITS) - 1u)
#define NODE_ROWS 128     // rows per node-score block (4 rows/thread)

// Fused kernel: blocks [0,NBLK) bin-sort their 4096-edge chunk into a private
// dense strip (no global atomics, no cursors); blocks [NBLK,...) compute
// per-node scores + out init. Phases are data-independent.
__global__ __launch_bounds__(THREADS)
void fused_kernel(const float4* __restrict__ x4,
                  const float4* __restrict__ Wrel4,
                  const float* __restrict__ b_rel,
                  const float4* __restrict__ Wroot4,
                  const int* __restrict__ ei,
                  float* __restrict__ s,
                  float* __restrict__ out,
                  unsigned* __restrict__ bucket,        // NBLK*STRIP uints
                  unsigned short* __restrict__ offs,    // NBLK*(NB+1) ushorts
                  int E, int NB, int NBLK, int n) {
    __shared__ __align__(16) unsigned lpair[K2_EPB];  // 16 KB
    __shared__ int  hist[THREADS];                    // 2 KB (then excl base)
    __shared__ int  wsum[8];

    int tid = threadIdx.x;

    if (blockIdx.x < NBLK) {
        // ---------------- binning phase ----------------
        int blk = blockIdx.x;
        hist[tid] = 0;
        __syncthreads();                               // barrier 1

        int base = blk * K2_EPB + tid * K2_U;
        int dst[K2_U], src[K2_U], rnk[K2_U], bin[K2_U];
        int have = 0;

        if (base + K2_U <= E) {
            const int4* sv = (const int4*)ei;          // src row
            const int4* dv = (const int4*)(ei + E);    // dst row
            int g = base >> 2;
            int4 s0 = sv[g], s1 = sv[g + 1];
            int4 d0 = dv[g], d1 = dv[g + 1];
            src[0] = s0.x; src[1] = s0.y; src[2] = s0.z; src[3] = s0.w;
            src[4] = s1.x; src[5] = s1.y; src[6] = s1.z; src[7] = s1.w;
            dst[0] = d0.x; dst[1] = d0.y; dst[2] = d0.z; dst[3] = d0.w;
            dst[4] = d1.x; dst[5] = d1.y; dst[6] = d1.z; dst[7] = d1.w;
            have = K2_U;
        } else {
            #pragma unroll
            for (int k = 0; k < K2_U; ++k) {
                int e = base + k;
                if (e < E) {
                    src[k] = ei[e];
                    dst[k] = ei[E + e];
                    have = k + 1;
                }
            }
        }

        #pragma unroll
        for (int k = 0; k < K2_U; ++k) {
            if (k < have) {
                bin[k] = dst[k] >> NPB_SHIFT;
                rnk[k] = atomicAdd(&hist[bin[k]], 1);
            }
        }
        __syncthreads();                               // barrier 2

        int h = hist[tid];

        // per-wave inclusive scan (no barriers)
        int lane = tid & 63;
        int w = tid >> 6;
        int incl = h;
        #pragma unroll
        for (int off = 1; off < 64; off <<= 1) {
            int v = __shfl_up(incl, off);
            if (lane >= off) incl += v;
        }
        if (lane == 63) wsum[w] = incl;
        __syncthreads();                               // barrier 3

        int wb = 0;
        #pragma unroll
        for (int i = 0; i < 8; ++i) wb += (i < w) ? wsum[i] : 0;
        int excl = wb + incl - h;                      // exclusive scan of hist

        // coalesced offsets row: offs[blk][tid] for tid in [0, NB]
        // (hist[b]=0 for b>NB-1, so excl at tid==NB equals nE = total pairs)
        if (tid <= NB)
            offs[(size_t)blk * (NB + 1) + tid] = (unsigned short)excl;

        hist[tid] = excl;                              // compaction base
        __syncthreads();                               // barrier 4

        #pragma unroll
        for (int k = 0; k < K2_U; ++k) {
            if (k < have) {
                int slot = hist[bin[k]] + rnk[k];      // bin-ordered LDS slot
                lpair[slot] = ((unsigned)(dst[k] & (NPB - 1)) << SRC_BITS)
                              | (unsigned)src[k];
            }
        }
        __syncthreads();                               // barrier 5

        // dense, perfectly-coalesced strip dump (uint4)
        int nE = min(K2_EPB, E - blk * K2_EPB);
        int n4 = (nE + 3) >> 2;
        const uint4* lp4 = (const uint4*)lpair;
        uint4* dp4 = (uint4*)(bucket + (size_t)blk * STRIP);
        for (int i = tid; i < n4; i += THREADS) dp4[i] = lp4[i];
    } else {
        // ---------------- node-score phase ----------------
        int nb = blockIdx.x - NBLK;
        int lane16 = tid & 15;
        int rg = tid >> 4;                  // 0..31
        int rowbase = nb * NODE_ROWS + rg;
        float4 wr = Wrel4[lane16];
        float4 wt = Wroot4[lane16];
        float b0 = b_rel[0];

        float4 xv[4];
        int row[4];
        #pragma unroll
        for (int k = 0; k < 4; ++k) {
            row[k] = rowbase + k * 32;
            xv[k] = (row[k] < n) ? x4[(size_t)row[k] * (DIM / 4) + lane16]
                                 : make_float4(0.f, 0.f, 0.f, 0.f);
        }
        #pragma unroll
        for (int k = 0; k < 4; ++k) {
            float sr = xv[k].x * wr.x + xv[k].y * wr.y
                     + xv[k].z * wr.z + xv[k].w * wr.w;
            float st = xv[k].x * wt.x + xv[k].y * wt.y
                     + xv[k].z * wt.z + xv[k].w * wt.w;
            #pragma unroll
            for (int off = 1; off < 16; off <<= 1) {
                sr += __shfl_xor(sr, off);
                st += __shfl_xor(st, off);
            }
            if (lane16 == 0 && row[k] < n) {
                s[row[k]]   = sr;
                out[row[k]] = st + b0;
            }
        }
    }
}

// Gather: one block per bucket. Thread t walks strip t's run
// [offs[t][b], offs[t][b+1]) — 293 independent run-walks in flight.
// offs table (229 KB) is L2-resident; each line reused by 32 buckets.
__global__ __launch_bounds__(THREADS)
void gather_kernel(const unsigned short* __restrict__ offs,
                   const unsigned* __restrict__ bucket,
                   const float* __restrict__ s,
                   float* __restrict__ out,
                   int NB, int NBLK, int n) {
    __shared__ float acc[NPB];
    int b = blockIdx.x;
    int tid = threadIdx.x;

    if (tid < NPB) acc[tid] = 0.f;
    __syncthreads();

    for (int strip = tid; strip < NBLK; strip += THREADS) {
        size_t ro = (size_t)strip * (NB + 1) + b;
        int o0 = offs[ro];
        int o1 = offs[ro + 1];
        const unsigned* sp = bucket + (size_t)strip * STRIP;
        for (int i = o0; i < o1; ++i) {
            unsigned p = sp[i];
            atomicAdd(&acc[p >> SRC_BITS], s[p & SRC_MASK]);
        }
    }
    __syncthreads();

    if (tid < NPB) {
        int g = b * NPB + tid;
        if (g < n) out[g] += acc[tid];
    }
}

extern "C" void kernel_launch(void* const* d_in, const int* in_sizes, int n_in,
                              void* d_out, int out_size, void* d_ws, size_t ws_size,
                              hipStream_t stream) {
    const float* x      = (const float*)d_in[0];
    const int*   ei     = (const int*)d_in[1];
    const float* W_rel  = (const float*)d_in[2];
    const float* b_rel  = (const float*)d_in[3];
    const float* W_root = (const float*)d_in[4];
    float* out = (float*)d_out;

    int n = out_size;                 // N_NODES = 100000
    int E = in_sizes[1] / 2;          // 1200000

    int NB   = (n + NPB - 1) / NPB;          // 391 buckets (<= THREADS)
    int NBLK = (E + K2_EPB - 1) / K2_EPB;    // 293 strips

    // ws layout: s [n f32] | offs [NBLK*(NB+1) u16] | bucket [NBLK*STRIP u32]
    float* s = (float*)d_ws;
    size_t off = ((size_t)n * 4 + 255) & ~(size_t)255;
    unsigned short* offs = (unsigned short*)((char*)d_ws + off);
    off += ((size_t)NBLK * (NB + 1) * 2 + 255) & ~(size_t)255;
    unsigned* bucket = (unsigned*)((char*)d_ws + off);

    // 1) fused: strip-binning blocks + node-score blocks (no memset needed)
    int NODEBLKS = (n + NODE_ROWS - 1) / NODE_ROWS;  // 782
    fused_kernel<<<NBLK + NODEBLKS, THREADS, 0, stream>>>(
        (const float4*)x, (const float4*)W_rel, b_rel, (const float4*)W_root,
        ei, s, out, bucket, offs, E, NB, NBLK, n);

    // 2) per-bucket run-walk accumulate + disjoint out RMW
    gather_kernel<<<NB, THREADS, 0, stream>>>(offs, bucket, s, out, NB, NBLK, n);
}

// Round 11
// 28.549 us; speedup vs baseline: 3.3507x; 1.1197x over previous
//
#include <hip/hip_runtime.h>

#define DIM 64
#define NPB 256           // nodes per bucket
#define NPB_SHIFT 8       // bin = dst >> 8
#define THREADS 512
#define K2_U 8
#define K2_EPB (THREADS * K2_U)   // 4096 edges per bin-block = strip size
#define STRIP K2_EPB
#define SRC_BITS 17
#define SRC_MASK ((1u << SRC_BITS) - 1u)
#define NODE_ROWS 160     // rows per node-score block (5 rows/thread)

// Fused kernel: blocks [0,NBLK) bin-sort their 4096-edge chunk into a private
// dense strip (no global atomics, no cursors); blocks [NBLK,...) compute
// per-node scores + out init. Phases are data-independent.
// Total blocks 293+625=918 <= 1024 resident -> single dispatch round.
__global__ __launch_bounds__(THREADS)
void fused_kernel(const float4* __restrict__ x4,
                  const float4* __restrict__ Wrel4,
                  const float* __restrict__ b_rel,
                  const float4* __restrict__ Wroot4,
                  const int* __restrict__ ei,
                  float* __restrict__ s,
                  float* __restrict__ out,
                  unsigned* __restrict__ bucket,        // NBLK*STRIP uints
                  unsigned short* __restrict__ offsT,   // (NB+1) x NBLK u16
                  int E, int NB, int NBLK, int n) {
    __shared__ __align__(16) unsigned lpair[K2_EPB];  // 16 KB
    __shared__ int  hist[THREADS];                    // 2 KB (then excl base)
    __shared__ int  wsum[8];

    int tid = threadIdx.x;

    if (blockIdx.x < NBLK) {
        // ---------------- binning phase ----------------
        int blk = blockIdx.x;
        hist[tid] = 0;
        __syncthreads();                               // barrier 1

        int base = blk * K2_EPB + tid * K2_U;
        int dst[K2_U], src[K2_U], rnk[K2_U], bin[K2_U];
        int have = 0;

        if (base + K2_U <= E) {
            const int4* sv = (const int4*)ei;          // src row
            const int4* dv = (const int4*)(ei + E);    // dst row
            int g = base >> 2;
            int4 s0 = sv[g], s1 = sv[g + 1];
            int4 d0 = dv[g], d1 = dv[g + 1];
            src[0] = s0.x; src[1] = s0.y; src[2] = s0.z; src[3] = s0.w;
            src[4] = s1.x; src[5] = s1.y; src[6] = s1.z; src[7] = s1.w;
            dst[0] = d0.x; dst[1] = d0.y; dst[2] = d0.z; dst[3] = d0.w;
            dst[4] = d1.x; dst[5] = d1.y; dst[6] = d1.z; dst[7] = d1.w;
            have = K2_U;
        } else {
            #pragma unroll
            for (int k = 0; k < K2_U; ++k) {
                int e = base + k;
                if (e < E) {
                    src[k] = ei[e];
                    dst[k] = ei[E + e];
                    have = k + 1;
                }
            }
        }

        #pragma unroll
        for (int k = 0; k < K2_U; ++k) {
            if (k < have) {
                bin[k] = dst[k] >> NPB_SHIFT;
                rnk[k] = atomicAdd(&hist[bin[k]], 1);
            }
        }
        __syncthreads();                               // barrier 2

        int h = hist[tid];

        // per-wave inclusive scan (no barriers)
        int lane = tid & 63;
        int w = tid >> 6;
        int incl = h;
        #pragma unroll
        for (int off = 1; off < 64; off <<= 1) {
            int v = __shfl_up(incl, off);
            if (lane >= off) incl += v;
        }
        if (lane == 63) wsum[w] = incl;
        __syncthreads();                               // barrier 3

        int wb = 0;
        #pragma unroll
        for (int i = 0; i < 8; ++i) wb += (i < w) ? wsum[i] : 0;
        int excl = wb + incl - h;                      // exclusive scan of hist

        // transposed offsets: offsT[bin][blk] (scattered stores, fire&forget;
        // gather reads each row contiguously). Row NB holds strip totals.
        if (tid <= NB)
            offsT[(size_t)tid * NBLK + blk] = (unsigned short)excl;

        hist[tid] = excl;                              // compaction base
        __syncthreads();                               // barrier 4

        #pragma unroll
        for (int k = 0; k < K2_U; ++k) {
            if (k < have) {
                int slot = hist[bin[k]] + rnk[k];      // bin-ordered LDS slot
                lpair[slot] = ((unsigned)(dst[k] & (NPB - 1)) << SRC_BITS)
                              | (unsigned)src[k];
            }
        }
        __syncthreads();                               // barrier 5

        // dense, perfectly-coalesced strip dump (uint4)
        int nE = min(K2_EPB, E - blk * K2_EPB);
        int n4 = (nE + 3) >> 2;
        const uint4* lp4 = (const uint4*)lpair;
        uint4* dp4 = (uint4*)(bucket + (size_t)blk * STRIP);
        for (int i = tid; i < n4; i += THREADS) dp4[i] = lp4[i];
    } else {
        // ---------------- node-score phase ----------------
        int nb = blockIdx.x - NBLK;
        int lane16 = tid & 15;
        int rg = tid >> 4;                  // 0..31
        int rowbase = nb * NODE_ROWS + rg;
        float4 wr = Wrel4[lane16];
        float4 wt = Wroot4[lane16];
        float b0 = b_rel[0];

        float4 xv[5];
        int row[5];
        #pragma unroll
        for (int k = 0; k < 5; ++k) {
            row[k] = rowbase + k * 32;
            xv[k] = (row[k] < n) ? x4[(size_t)row[k] * (DIM / 4) + lane16]
                                 : make_float4(0.f, 0.f, 0.f, 0.f);
        }
        #pragma unroll
        for (int k = 0; k < 5; ++k) {
            float sr = xv[k].x * wr.x + xv[k].y * wr.y
                     + xv[k].z * wr.z + xv[k].w * wr.w;
            float st = xv[k].x * wt.x + xv[k].y * wt.y
                     + xv[k].z * wt.z + xv[k].w * wt.w;
            #pragma unroll
            for (int off = 1; off < 16; off <<= 1) {
                sr += __shfl_xor(sr, off);
                st += __shfl_xor(st, off);
            }
            if (lane16 == 0 && row[k] < n) {
                s[row[k]]   = sr;
                out[row[k]] = st + b0;
            }
        }
    }
}

// Gather: one block per bucket. Stage offs rows b,b+1 (contiguous) into LDS;
// thread t walks strip t's run with uint4-vectorized loads; LDS accumulate;
// plain RMW of disjoint out slice.
__global__ __launch_bounds__(THREADS)
void gather_kernel(const unsigned short* __restrict__ offsT,
                   const unsigned* __restrict__ bucket,
                   const float* __restrict__ s,
                   float* __restrict__ out,
                   int NB, int NBLK, int n) {
    __shared__ float acc[NPB];
    __shared__ unsigned short o0s[THREADS], o1s[THREADS];
    int b = blockIdx.x;
    int tid = threadIdx.x;

    if (tid < NPB) acc[tid] = 0.f;
    for (int t = tid; t < NBLK; t += THREADS) {
        o0s[t] = offsT[(size_t)b * NBLK + t];        // coalesced row read
        o1s[t] = offsT[(size_t)(b + 1) * NBLK + t];
    }
    __syncthreads();

    if (tid < NBLK) {
        int o0 = o0s[tid];
        int o1 = o1s[tid];
        const unsigned* sp = bucket + (size_t)tid * STRIP;
        int i = o0;
        for (; i < o1 && (i & 3); ++i) {
            unsigned p = sp[i];
            atomicAdd(&acc[p >> SRC_BITS], s[p & SRC_MASK]);
        }
        for (; i + 4 <= o1; i += 4) {
            uint4 q = *(const uint4*)(sp + i);
            float v0 = s[q.x & SRC_MASK];
            float v1 = s[q.y & SRC_MASK];
            float v2 = s[q.z & SRC_MASK];
            float v3 = s[q.w & SRC_MASK];
            atomicAdd(&acc[q.x >> SRC_BITS], v0);
            atomicAdd(&acc[q.y >> SRC_BITS], v1);
            atomicAdd(&acc[q.z >> SRC_BITS], v2);
            atomicAdd(&acc[q.w >> SRC_BITS], v3);
        }
        for (; i < o1; ++i) {
            unsigned p = sp[i];
            atomicAdd(&acc[p >> SRC_BITS], s[p & SRC_MASK]);
        }
    }
    __syncthreads();

    if (tid < NPB) {
        int g = b * NPB + tid;
        if (g < n) out[g] += acc[tid];
    }
}

extern "C" void kernel_launch(void* const* d_in, const int* in_sizes, int n_in,
                              void* d_out, int out_size, void* d_ws, size_t ws_size,
                              hipStream_t stream) {
    const float* x      = (const float*)d_in[0];
    const int*   ei     = (const int*)d_in[1];
    const float* W_rel  = (const float*)d_in[2];
    const float* b_rel  = (const float*)d_in[3];
    const float* W_root = (const float*)d_in[4];
    float* out = (float*)d_out;

    int n = out_size;                 // N_NODES = 100000
    int E = in_sizes[1] / 2;          // 1200000

    int NB   = (n + NPB - 1) / NPB;          // 391 buckets (<= THREADS)
    int NBLK = (E + K2_EPB - 1) / K2_EPB;    // 293 strips

    // ws layout: s [n f32] | offsT [(NB+1)*NBLK u16] | bucket [NBLK*STRIP u32]
    float* s = (float*)d_ws;
    size_t off = ((size_t)n * 4 + 255) & ~(size_t)255;
    unsigned short* offsT = (unsigned short*)((char*)d_ws + off);
    off += ((size_t)(NB + 1) * NBLK * 2 + 255) & ~(size_t)255;
    unsigned* bucket = (unsigned*)((char*)d_ws + off);

    // 1) fused: strip-binning blocks + node-score blocks (918 blocks total)
    int NODEBLKS = (n + NODE_ROWS - 1) / NODE_ROWS;  // 625
    fused_kernel<<<NBLK + NODEBLKS, THREADS, 0, stream>>>(
        (const float4*)x, (const float4*)W_rel, b_rel, (const float4*)W_root,
        ei, s, out, bucket, offsT, E, NB, NBLK, n);

    // 2) per-bucket run-walk accumulate + disjoint out RMW
    gather_kernel<<<NB, THREADS, 0, stream>>>(offsT, bucket, s, out, NB, NBLK, n);
}